// Round 1
// baseline (2148.954 us; speedup 1.0000x reference)
//
#include <hip/hip_runtime.h>
#include <hip/hip_bf16.h>
#include <math.h>

// Problem constants
#define B_   2
#define S_   2048
#define C_   512
#define D_   768
#define H_   12
#define DH_  64
#define DFF_ 3072
#define NS_  (C_ + S_)   // 2560

// ---------------------------------------------------------------------------
// LayerNorm over D=768. One block (256 threads) per row; 3 elements/thread.
// ---------------------------------------------------------------------------
__global__ __launch_bounds__(256) void ln_kernel(const float* __restrict__ in,
                                                 const float* __restrict__ g,
                                                 const float* __restrict__ bta,
                                                 float* __restrict__ out)
{
    int row = blockIdx.x;
    int tid = threadIdx.x;
    const float* x = in + (size_t)row * D_;
    float v0 = x[tid], v1 = x[tid + 256], v2 = x[tid + 512];
    float s  = v0 + v1 + v2;
    float s2 = v0 * v0 + v1 * v1 + v2 * v2;
#pragma unroll
    for (int off = 32; off >= 1; off >>= 1) {
        s  += __shfl_down(s,  off, 64);
        s2 += __shfl_down(s2, off, 64);
    }
    __shared__ float sh[8];
    int lane = tid & 63, wv = tid >> 6;
    if (lane == 0) { sh[wv] = s; sh[4 + wv] = s2; }
    __syncthreads();
    s  = sh[0] + sh[1] + sh[2] + sh[3];
    s2 = sh[4] + sh[5] + sh[6] + sh[7];
    float mu   = s * (1.0f / D_);
    float var  = s2 * (1.0f / D_) - mu * mu;
    float rstd = rsqrtf(var + 1e-5f);
    float* o = out + (size_t)row * D_;
    o[tid]       = (v0 - mu) * rstd * g[tid]       + bta[tid];
    o[tid + 256] = (v1 - mu) * rstd * g[tid + 256] + bta[tid + 256];
    o[tid + 512] = (v2 - mu) * rstd * g[tid + 512] + bta[tid + 512];
}

// ---------------------------------------------------------------------------
// Tiled fp32 GEMM: C[M,N] = A[M,K] @ W[K,N] + bias (+silu) (+resid) (+slice)
// 64x64 block tile, 256 threads (16x16), 4x4 per-thread microtile, K-step 16.
// All M,N multiples of 64; K multiple of 16 (asserted by call sites).
// ---------------------------------------------------------------------------
template <int ACT, int RESID, int SLICE>
__global__ __launch_bounds__(256) void gemm64(const float* __restrict__ A,
                                              const float* __restrict__ W,
                                              const float* __restrict__ bias,
                                              const float* __restrict__ resid,
                                              float* __restrict__ Cout,
                                              int M, int N, int K)
{
    __shared__ float As[16][68];   // [k][m], +4 pad kills 16-way store conflict
    __shared__ float Ws[16][68];   // [k][n]
    int tid = threadIdx.x;
    int tx = tid & 15, ty = tid >> 4;          // output microtile coords
    int mb = blockIdx.y * 64, nb = blockIdx.x * 64;
    int lr = tid >> 4, lk = tid & 15;          // A staging: row, k
    int wn = tid & 63, wk = tid >> 6;          // W staging: n, k
    float acc[4][4] = {};
    const float* Aptr = A + (size_t)(mb + lr) * K + lk;
    const float* Wptr = W + (size_t)wk * N + nb + wn;

    for (int kk = 0; kk < K; kk += 16) {
        __syncthreads();
#pragma unroll
        for (int i = 0; i < 4; ++i)
            As[lk][lr + 16 * i] = Aptr[(size_t)(16 * i) * K + kk];
#pragma unroll
        for (int i = 0; i < 4; ++i)
            Ws[wk + 4 * i][wn] = Wptr[(size_t)(kk + 4 * i) * N];
        __syncthreads();
#pragma unroll
        for (int k = 0; k < 16; ++k) {
            float4 a4 = *(const float4*)&As[k][ty * 4];
            float4 w4 = *(const float4*)&Ws[k][tx * 4];
            float av[4] = {a4.x, a4.y, a4.z, a4.w};
            float wv[4] = {w4.x, w4.y, w4.z, w4.w};
#pragma unroll
            for (int i = 0; i < 4; ++i)
#pragma unroll
                for (int j = 0; j < 4; ++j)
                    acc[i][j] = fmaf(av[i], wv[j], acc[i][j]);
        }
    }

    float4 bv = *(const float4*)&bias[nb + tx * 4];
    float bvv[4] = {bv.x, bv.y, bv.z, bv.w};
#pragma unroll
    for (int i = 0; i < 4; ++i) {
        int row = mb + ty * 4 + i;
        float v[4];
#pragma unroll
        for (int j = 0; j < 4; ++j) v[j] = acc[i][j] + bvv[j];
        if (ACT == 1) {
#pragma unroll
            for (int j = 0; j < 4; ++j) v[j] = v[j] / (1.0f + __expf(-v[j]));
        }
        if (RESID) {
            float4 rv = *(const float4*)&resid[(size_t)row * N + nb + tx * 4];
            v[0] += rv.x; v[1] += rv.y; v[2] += rv.z; v[3] += rv.w;
        }
        float4 ov; ov.x = v[0]; ov.y = v[1]; ov.z = v[2]; ov.w = v[3];
        if (SLICE) {
            int bb = row >> 11, ss = row & (S_ - 1);   // S_=2048 rows per batch
            if (ss > 0)
                *(float4*)&Cout[((size_t)(bb * (S_ - 1) + ss - 1)) * N + nb + tx * 4] = ov;
        } else {
            *(float4*)&Cout[(size_t)row * N + nb + tx * 4] = ov;
        }
    }
}

// ---------------------------------------------------------------------------
// Fused attention (flash-style, fp32). One block = (b, h, 64-row Q tile).
// 256 threads = 64 rows x 4 quads; each thread owns 16 output dims.
// Keys: cols [0,512) from kv_ctx, cols [512,2560) from self qkv.
// Mask: valid iff kj <= qi+512 and kj != qi (smp>0). Bias +cab on kj<512.
// ---------------------------------------------------------------------------
__global__ __launch_bounds__(256) void attn_kernel(const float* __restrict__ qkv,
                                                   const float* __restrict__ kvctx,
                                                   const float* __restrict__ cabp,
                                                   const int* __restrict__ smpp,
                                                   float* __restrict__ aout)
{
    __shared__ float qs[64][68];
    __shared__ float ks[64][68];   // K tile, then reused for V tile
    __shared__ float ps[64][68];   // probabilities

    int qt = blockIdx.x, h = blockIdx.y, b = blockIdx.z;
    int tid = threadIdx.x;
    float cab = *cabp;
    int   smp = *smpp;             // int 1 (or float 1.0 bits) -> >0 either way
    int qbase = qt * 64;

    for (int e = tid; e < 4096; e += 256) {
        int rr = e >> 6, d = e & 63;
        qs[rr][d] = qkv[((size_t)(b * S_ + qbase + rr)) * (3 * D_) + h * DH_ + d];
    }
    __syncthreads();

    int r = tid >> 2, q4 = tid & 3;
    float o[16];
#pragma unroll
    for (int j = 0; j < 16; ++j) o[j] = 0.0f;
    float m = -1e30f, l = 0.0f;
    int qi = qbase + r;

    int ntiles = qt + 9;   // max kj = qi_max + 512 -> tile qt+8 inclusive
    for (int t = 0; t < ntiles; ++t) {
        int kb = t * 64;
        // ---- stage K tile ----
        for (int e = tid; e < 4096; e += 256) {
            int kr = e >> 6, d = e & 63;
            int kj = kb + kr;
            float val;
            if (kj < C_)
                val = kvctx[((size_t)(b * C_ + kj)) * (2 * D_) + h * DH_ + d];
            else
                val = qkv[((size_t)(b * S_ + kj - C_)) * (3 * D_) + D_ + h * DH_ + d];
            ks[kr][d] = val;
        }
        __syncthreads();

        // ---- scores: 16 per thread (cols q4*16..q4*16+15) ----
        float sc[16];
#pragma unroll
        for (int j = 0; j < 16; ++j) sc[j] = 0.0f;
#pragma unroll 4
        for (int d4 = 0; d4 < 16; ++d4) {
            float4 qv = *(const float4*)&qs[r][d4 * 4];
#pragma unroll
            for (int j = 0; j < 16; ++j) {
                float4 kv = *(const float4*)&ks[q4 * 16 + j][d4 * 4];
                sc[j] = fmaf(qv.x, kv.x, fmaf(qv.y, kv.y,
                         fmaf(qv.z, kv.z, fmaf(qv.w, kv.w, sc[j]))));
            }
        }

        // ---- mask + bias + online softmax ----
        float tmax = -1e30f;
#pragma unroll
        for (int j = 0; j < 16; ++j) {
            int kj = kb + q4 * 16 + j;
            bool valid = (kj <= qi + C_) && !((smp > 0) && (kj == qi));
            float v = valid ? sc[j] : -10000.0f;
            if (kj < C_) v += cab;
            sc[j] = v;
            tmax = fmaxf(tmax, v);
        }
        tmax = fmaxf(tmax, __shfl_xor(tmax, 1, 64));
        tmax = fmaxf(tmax, __shfl_xor(tmax, 2, 64));
        float mnew = fmaxf(m, tmax);
        float lsum = 0.0f;
#pragma unroll
        for (int j = 0; j < 16; ++j) {
            float p = __expf(sc[j] - mnew);
            ps[r][q4 * 16 + j] = p;
            lsum += p;
        }
        lsum += __shfl_xor(lsum, 1, 64);
        lsum += __shfl_xor(lsum, 2, 64);
        float scale = __expf(m - mnew);
        l = l * scale + lsum;
        m = mnew;
#pragma unroll
        for (int j = 0; j < 16; ++j) o[j] *= scale;
        __syncthreads();   // all waves done reading K tile

        // ---- stage V tile (reuse ks) ----
        for (int e = tid; e < 4096; e += 256) {
            int kr = e >> 6, d = e & 63;
            int kj = kb + kr;
            float val;
            if (kj < C_)
                val = kvctx[((size_t)(b * C_ + kj)) * (2 * D_) + D_ + h * DH_ + d];
            else
                val = qkv[((size_t)(b * S_ + kj - C_)) * (3 * D_) + 2 * D_ + h * DH_ + d];
            ks[kr][d] = val;
        }
        __syncthreads();

        // ---- PV: o[d] += p[r][c] * v[c][d] ----
#pragma unroll 4
        for (int c = 0; c < 64; ++c) {
            float p = ps[r][c];
            const float* vrow = &ks[c][q4 * 16];
#pragma unroll
            for (int j = 0; j < 4; ++j) {
                float4 v4 = *(const float4*)&vrow[j * 4];
                o[j * 4 + 0] = fmaf(p, v4.x, o[j * 4 + 0]);
                o[j * 4 + 1] = fmaf(p, v4.y, o[j * 4 + 1]);
                o[j * 4 + 2] = fmaf(p, v4.z, o[j * 4 + 2]);
                o[j * 4 + 3] = fmaf(p, v4.w, o[j * 4 + 3]);
            }
        }
        __syncthreads();   // done with V tile + ps before next iteration
    }

    float inv = 1.0f / l;
    float* dst = aout + ((size_t)(b * S_ + qi)) * D_ + h * DH_ + q4 * 16;
#pragma unroll
    for (int j = 0; j < 16; ++j) dst[j] = o[j] * inv;
}

// ---------------------------------------------------------------------------
extern "C" void kernel_launch(void* const* d_in, const int* in_sizes, int n_in,
                              void* d_out, int out_size, void* d_ws, size_t ws_size,
                              hipStream_t stream)
{
    const float* x     = (const float*)d_in[0];
    const float* ctx   = (const float*)d_in[1];
    const float* ln1g  = (const float*)d_in[2];
    const float* ln1b  = (const float*)d_in[3];
    const float* Wattn = (const float*)d_in[4];
    const float* battn = (const float*)d_in[5];
    const float* Wref  = (const float*)d_in[6];
    const float* bref  = (const float*)d_in[7];
    const float* Wproj = (const float*)d_in[8];
    const float* bproj = (const float*)d_in[9];
    const float* ln2g  = (const float*)d_in[10];
    const float* ln2b  = (const float*)d_in[11];
    const float* W1    = (const float*)d_in[12];
    const float* b1    = (const float*)d_in[13];
    const float* W2    = (const float*)d_in[14];
    const float* b2    = (const float*)d_in[15];
    const float* cab   = (const float*)d_in[16];
    const int*   smp   = (const int*)d_in[17];
    float* out = (float*)d_out;

    // workspace layout (floats); h2 reuses h1, ff1 reuses qkv+kvctx+attn
    float* ws = (float*)d_ws;
    const size_t R = (size_t)B_ * S_;                    // 4096
    float* h1h2  = ws;                                   // 3,145,728
    float* qkv   = ws + R * D_;                          // 9,437,184
    float* kvctx = qkv + R * 3 * D_;                     // 1,572,864
    float* attn  = kvctx + (size_t)B_ * C_ * 2 * D_;     // 3,145,728
    float* x1    = attn + R * D_;                        // 3,145,728
    float* ff1   = qkv;                                  // spans 14.1M >= 12.6M

    // 1. h1 = LN1(x)
    ln_kernel<<<R, 256, 0, stream>>>(x, ln1g, ln1b, h1h2);
    // 2. qkv = h1 @ Wattn + battn
    gemm64<0,0,0><<<dim3(3 * D_ / 64, R / 64), 256, 0, stream>>>(
        h1h2, Wattn, battn, nullptr, qkv, (int)R, 3 * D_, D_);
    // 3. kvctx = ctx @ Wref + bref
    gemm64<0,0,0><<<dim3(2 * D_ / 64, B_ * C_ / 64), 256, 0, stream>>>(
        ctx, Wref, bref, nullptr, kvctx, B_ * C_, 2 * D_, D_);
    // 4. attention
    attn_kernel<<<dim3(S_ / 64, H_, B_), 256, 0, stream>>>(qkv, kvctx, cab, smp, attn);
    // 5. x1 = x + attn @ Wproj + bproj
    gemm64<0,1,0><<<dim3(D_ / 64, R / 64), 256, 0, stream>>>(
        attn, Wproj, bproj, x, x1, (int)R, D_, D_);
    // 6. h2 = LN2(x1)
    ln_kernel<<<R, 256, 0, stream>>>(x1, ln2g, ln2b, h1h2);
    // 7. ff1 = silu(h2 @ W1 + b1)
    gemm64<1,0,0><<<dim3(DFF_ / 64, R / 64), 256, 0, stream>>>(
        h1h2, W1, b1, nullptr, ff1, (int)R, DFF_, D_);
    // 8. out = slice(x1 + ff1 @ W2 + b2)
    gemm64<0,1,1><<<dim3(D_ / 64, R / 64), 256, 0, stream>>>(
        ff1, W2, b2, x1, out, (int)R, D_, DFF_);
}

// Round 3
// 924.919 us; speedup vs baseline: 2.3234x; 2.3234x over previous
//
#include <hip/hip_runtime.h>
#include <hip/hip_bf16.h>
#include <math.h>

// Problem constants
#define B_   2
#define S_   2048
#define C_   512
#define D_   768
#define H_   12
#define DH_  64
#define DFF_ 3072
#define NS_  (C_ + S_)   // 2560

typedef __attribute__((ext_vector_type(8))) short          bf16x8;
typedef __attribute__((ext_vector_type(4))) float          f32x4;
typedef __attribute__((ext_vector_type(8))) unsigned short us8;
typedef __attribute__((ext_vector_type(4))) unsigned short us4;

static __device__ __forceinline__ unsigned short f2b(float f) {
    unsigned int u = __float_as_uint(f);
    unsigned int r = (u + 0x7FFFu + ((u >> 16) & 1u)) >> 16;   // RNE
    return (unsigned short)r;
}
static __device__ __forceinline__ float b2f(unsigned short u) {
    return __uint_as_float(((unsigned int)u) << 16);
}

// async global->LDS, 16B per lane; lptr must be wave-uniform base
#define ASYNC_LDS16(gp, lp)                                                     \
    __builtin_amdgcn_global_load_lds(                                           \
        (const __attribute__((address_space(1))) void*)(gp),                    \
        (__attribute__((address_space(3))) void*)(lp), 16, 0, 0)

// ---------------------------------------------------------------------------
// LayerNorm over D=768 -> bf16 out. One block (256 threads) per row.
// ---------------------------------------------------------------------------
__global__ __launch_bounds__(256) void ln_kernel(const float* __restrict__ in,
                                                 const float* __restrict__ g,
                                                 const float* __restrict__ bta,
                                                 unsigned short* __restrict__ out)
{
    int row = blockIdx.x;
    int tid = threadIdx.x;
    const float* x = in + (size_t)row * D_;
    float v0 = x[tid], v1 = x[tid + 256], v2 = x[tid + 512];
    float s  = v0 + v1 + v2;
    float s2 = v0 * v0 + v1 * v1 + v2 * v2;
#pragma unroll
    for (int off = 32; off >= 1; off >>= 1) {
        s  += __shfl_down(s,  off, 64);
        s2 += __shfl_down(s2, off, 64);
    }
    __shared__ float sh[8];
    int lane = tid & 63, wv = tid >> 6;
    if (lane == 0) { sh[wv] = s; sh[4 + wv] = s2; }
    __syncthreads();
    s  = sh[0] + sh[1] + sh[2] + sh[3];
    s2 = sh[4] + sh[5] + sh[6] + sh[7];
    float mu   = s * (1.0f / D_);
    float var  = s2 * (1.0f / D_) - mu * mu;
    float rstd = rsqrtf(var + 1e-5f);
    unsigned short* o = out + (size_t)row * D_;
    o[tid]       = f2b((v0 - mu) * rstd * g[tid]       + bta[tid]);
    o[tid + 256] = f2b((v1 - mu) * rstd * g[tid + 256] + bta[tid + 256]);
    o[tid + 512] = f2b((v2 - mu) * rstd * g[tid + 512] + bta[tid + 512]);
}

// ---------------------------------------------------------------------------
// Weight convert+transpose: fp32 [K][N] -> bf16 [N][K]. 32x32 tiles.
// ---------------------------------------------------------------------------
__global__ __launch_bounds__(256) void wconv_t(const float* __restrict__ in,
                                               unsigned short* __restrict__ out,
                                               int K, int N)
{
    __shared__ float t[32][33];
    int n0 = blockIdx.x * 32, k0 = blockIdx.y * 32;
    int tx = threadIdx.x & 31, ty = threadIdx.x >> 5;
#pragma unroll
    for (int i = 0; i < 32; i += 8)
        t[ty + i][tx] = in[(size_t)(k0 + ty + i) * N + n0 + tx];
    __syncthreads();
#pragma unroll
    for (int i = 0; i < 32; i += 8)
        out[(size_t)(n0 + ty + i) * K + k0 + tx] = f2b(t[tx][ty + i]);
}

// fp32 -> bf16 elementwise (n must be multiple of 4)
__global__ __launch_bounds__(256) void f2b_vec(const float* __restrict__ in,
                                               unsigned short* __restrict__ out, int n4)
{
    int i = blockIdx.x * 256 + threadIdx.x;
    if (i < n4) {
        float4 v = ((const float4*)in)[i];
        us4 o = { f2b(v.x), f2b(v.y), f2b(v.z), f2b(v.w) };
        ((us4*)out)[i] = o;
    }
}

// ---------------------------------------------------------------------------
// MFMA bf16 GEMM (m97 structure): C[M,N] = A[M,K] @ BT[N,K]^T + bias
// 128x128 tile, BK=64, 256 threads = 4 waves (2x2), each wave 64x64 (4x4 frags
// of 16x16x32). global_load_lds width-16 staging, linear LDS.
// ---------------------------------------------------------------------------
template <int ACT, int RESID, int SLICE, int OUTBF>
__global__ __launch_bounds__(256) void gemm_mfma(
    const unsigned short* __restrict__ A,    // [M][K] bf16
    const unsigned short* __restrict__ BT,   // [N][K] bf16
    const float* __restrict__ bias,          // [N]
    const float* __restrict__ resid,         // [M][N] fp32 (if RESID)
    float* __restrict__ outf,                // if !OUTBF
    unsigned short* __restrict__ outb,       // if OUTBF
    int M, int N, int K)
{
    __shared__ unsigned short Als[128 * 64];  // 16KB, row-major [row][k]
    __shared__ unsigned short Bls[128 * 64];  // 16KB

    int tid  = threadIdx.x;
    int lane = tid & 63, w = tid >> 6;
    int mb = blockIdx.y * 128, nb = blockIdx.x * 128;
    int wr = w >> 1, wc = w & 1;

    f32x4 acc[4][4];
#pragma unroll
    for (int m = 0; m < 4; ++m)
#pragma unroll
        for (int n = 0; n < 4; ++n)
            acc[m][n] = (f32x4){0.f, 0.f, 0.f, 0.f};

    // staging geometry: wave w covers rows w*32..w*32+31 in 4 issues of 8 rows
    int srow = w * 32 + (lane >> 3);          // +8 per issue
    int scol = (lane & 7) * 8;                // ushort col
    const unsigned short* abase = A  + (size_t)(mb + srow) * K + scol;
    const unsigned short* bbase = BT + (size_t)(nb + srow) * K + scol;

    int arow_l = wr * 64 + (lane & 15);       // +m*16, fragment row
    int brow_l = wc * 64 + (lane & 15);       // +n*16
    int kfrag  = (lane >> 4) * 8;             // fragment k offset

    for (int kk = 0; kk < K; kk += 64) {
        __syncthreads();
#pragma unroll
        for (int i = 0; i < 4; ++i) {
            ASYNC_LDS16(abase + (size_t)(i * 8) * K + kk,
                        (char*)Als + (w * 32 + i * 8) * 128);
            ASYNC_LDS16(bbase + (size_t)(i * 8) * K + kk,
                        (char*)Bls + (w * 32 + i * 8) * 128);
        }
        __syncthreads();
#pragma unroll
        for (int ks = 0; ks < 64; ks += 32) {
            bf16x8 af[4], bq[4];
#pragma unroll
            for (int m = 0; m < 4; ++m)
                af[m] = *(const bf16x8*)&Als[(arow_l + m * 16) * 64 + ks + kfrag];
#pragma unroll
            for (int n = 0; n < 4; ++n)
                bq[n] = *(const bf16x8*)&Bls[(brow_l + n * 16) * 64 + ks + kfrag];
#pragma unroll
            for (int m = 0; m < 4; ++m)
#pragma unroll
                for (int n = 0; n < 4; ++n)
                    acc[m][n] = __builtin_amdgcn_mfma_f32_16x16x32_bf16(
                        af[m], bq[n], acc[m][n], 0, 0, 0);
        }
    }

    // epilogue: D layout col=lane&15, row=(lane>>4)*4+reg
#pragma unroll
    for (int m = 0; m < 4; ++m) {
        int grow0 = mb + wr * 64 + m * 16 + ((lane >> 4) << 2);
#pragma unroll
        for (int n = 0; n < 4; ++n) {
            int gcol = nb + wc * 64 + n * 16 + (lane & 15);
            float bv = bias[gcol];
#pragma unroll
            for (int q = 0; q < 4; ++q) {
                float v = acc[m][n][q] + bv;
                if (ACT) v = v / (1.0f + __expf(-v));
                int grow = grow0 + q;
                if (RESID) v += resid[(size_t)grow * N + gcol];
                if (OUTBF) {
                    outb[(size_t)grow * N + gcol] = f2b(v);
                } else if (SLICE) {
                    int bb = grow >> 11, ss = grow & 2047;
                    if (ss > 0)
                        outf[((size_t)(bb * 2047 + ss - 1)) * N + gcol] = v;
                } else {
                    outf[(size_t)grow * N + gcol] = v;
                }
            }
        }
    }
}

// ---------------------------------------------------------------------------
// Fused attention (flash-style, fp32 math, bf16 I/O). Block = (qtile,h,b).
// 256 threads = 64 rows x 4 quads. K/V tile in swizzled LDS (XOR block swz:
// pblk = blk ^ ((row>>4)&3) kills the 4-way q4-group conflict at row
// stride 64 floats). ps stride 65 (==1 mod 32 -> 2-way = free).
// ---------------------------------------------------------------------------
__global__ __launch_bounds__(256) void attn_kernel(const unsigned short* __restrict__ qkv,
                                                   const unsigned short* __restrict__ kvctx,
                                                   const float* __restrict__ cabp,
                                                   const int* __restrict__ smpp,
                                                   unsigned short* __restrict__ aout)
{
    __shared__ float qs[64 * 68];
    __shared__ float ks[64 * 64];   // K tile, then V tile (swizzled)
    __shared__ float ps[64 * 65];

    int qt = blockIdx.x, h = blockIdx.y, b = blockIdx.z;
    int tid = threadIdx.x;
    float cab = *cabp;
    int   smp = *smpp;
    int qbase = qt * 64;

    int r  = tid >> 2;      // row 0..63
    int q4 = tid & 3;       // quad 0..3
    int qi = qbase + r;
    int sw_r = (r >> 4) & 3;

    // ---- stage Q: thread loads 16 bf16 of row r at cols q4*16.. ----
    {
        const us8* src = (const us8*)&qkv[((size_t)(b * S_ + qbase + r)) * (3 * D_) + h * DH_ + q4 * 16];
        us8 v0 = src[0], v1 = src[1];
        float* dst = &qs[r * 68 + q4 * 16];
#pragma unroll
        for (int g = 0; g < 8; ++g) { dst[g] = b2f(v0[g]); dst[8 + g] = b2f(v1[g]); }
    }
    __syncthreads();

    float o[16];
#pragma unroll
    for (int j = 0; j < 16; ++j) o[j] = 0.0f;
    float m = -1e30f, l = 0.0f;

    int ntiles = qt + 9;   // max kj = qi_max + 512 -> tile qt+8 inclusive
    for (int t = 0; t < ntiles; ++t) {
        int kb = t * 64;
        // ---- stage K tile (swizzled) ----
        {
            int kj = kb + r;
            const unsigned short* sp = (kj < C_)
                ? &kvctx[((size_t)(b * C_ + kj)) * (2 * D_) + h * DH_ + q4 * 16]
                : &qkv[((size_t)(b * S_ + kj - C_)) * (3 * D_) + D_ + h * DH_ + q4 * 16];
            us8 v0 = ((const us8*)sp)[0], v1 = ((const us8*)sp)[1];
            float tmp[16];
#pragma unroll
            for (int g = 0; g < 8; ++g) { tmp[g] = b2f(v0[g]); tmp[8 + g] = b2f(v1[g]); }
#pragma unroll
            for (int g = 0; g < 4; ++g) {
                int pblk = (q4 * 4 + g) ^ sw_r;
                float4 f4 = { tmp[g * 4], tmp[g * 4 + 1], tmp[g * 4 + 2], tmp[g * 4 + 3] };
                *(float4*)&ks[r * 64 + pblk * 4] = f4;
            }
        }
        __syncthreads();

        // ---- scores: 16 per thread (cols q4*16..q4*16+15) ----
        float sc[16];
#pragma unroll
        for (int j = 0; j < 16; ++j) sc[j] = 0.0f;
#pragma unroll 4
        for (int d4 = 0; d4 < 16; ++d4) {
            float4 qv = *(const float4*)&qs[r * 68 + d4 * 4];
#pragma unroll
            for (int j = 0; j < 16; ++j) {
                // row = q4*16+j  ->  (row>>4)&3 == q4
                float4 kv = *(const float4*)&ks[(q4 * 16 + j) * 64 + ((d4 ^ q4) << 2)];
                sc[j] = fmaf(qv.x, kv.x, fmaf(qv.y, kv.y,
                         fmaf(qv.z, kv.z, fmaf(qv.w, kv.w, sc[j]))));
            }
        }

        // ---- mask + bias + online softmax ----
        float tmax = -1e30f;
#pragma unroll
        for (int j = 0; j < 16; ++j) {
            int kj = kb + q4 * 16 + j;
            bool valid = (kj <= qi + C_) && !((smp > 0) && (kj == qi));
            float v = valid ? sc[j] : -10000.0f;
            if (kj < C_) v += cab;
            sc[j] = v;
            tmax = fmaxf(tmax, v);
        }
        tmax = fmaxf(tmax, __shfl_xor(tmax, 1, 64));
        tmax = fmaxf(tmax, __shfl_xor(tmax, 2, 64));
        float mnew = fmaxf(m, tmax);
        float lsum = 0.0f;
#pragma unroll
        for (int j = 0; j < 16; ++j) {
            float p = __expf(sc[j] - mnew);
            ps[r * 65 + q4 * 16 + j] = p;
            lsum += p;
        }
        lsum += __shfl_xor(lsum, 1, 64);
        lsum += __shfl_xor(lsum, 2, 64);
        float scale = __expf(m - mnew);
        l = l * scale + lsum;
        m = mnew;
#pragma unroll
        for (int j = 0; j < 16; ++j) o[j] *= scale;
        __syncthreads();   // all waves done reading K tile

        // ---- stage V tile (reuse ks, swizzled) ----
        {
            int kj = kb + r;
            const unsigned short* sp = (kj < C_)
                ? &kvctx[((size_t)(b * C_ + kj)) * (2 * D_) + D_ + h * DH_ + q4 * 16]
                : &qkv[((size_t)(b * S_ + kj - C_)) * (3 * D_) + 2 * D_ + h * DH_ + q4 * 16];
            us8 v0 = ((const us8*)sp)[0], v1 = ((const us8*)sp)[1];
            float tmp[16];
#pragma unroll
            for (int g = 0; g < 8; ++g) { tmp[g] = b2f(v0[g]); tmp[8 + g] = b2f(v1[g]); }
#pragma unroll
            for (int g = 0; g < 4; ++g) {
                int pblk = (q4 * 4 + g) ^ sw_r;
                float4 f4 = { tmp[g * 4], tmp[g * 4 + 1], tmp[g * 4 + 2], tmp[g * 4 + 3] };
                *(float4*)&ks[r * 64 + pblk * 4] = f4;
            }
        }
        __syncthreads();

        // ---- PV: o[d] += p[r][c] * v[c][d] ----
#pragma unroll 4
        for (int c = 0; c < 64; ++c) {
            float p = ps[r * 65 + c];
            int cs = (c >> 4) & 3;
#pragma unroll
            for (int jj = 0; jj < 4; ++jj) {
                float4 v4 = *(const float4*)&ks[c * 64 + (((q4 * 4 + jj) ^ cs) << 2)];
                o[jj * 4 + 0] = fmaf(p, v4.x, o[jj * 4 + 0]);
                o[jj * 4 + 1] = fmaf(p, v4.y, o[jj * 4 + 1]);
                o[jj * 4 + 2] = fmaf(p, v4.z, o[jj * 4 + 2]);
                o[jj * 4 + 3] = fmaf(p, v4.w, o[jj * 4 + 3]);
            }
        }
        __syncthreads();   // done with V tile + ps before next iteration
    }

    float inv = 1.0f / l;
    unsigned short* dst = &aout[((size_t)(b * S_ + qi)) * D_ + h * DH_ + q4 * 16];
#pragma unroll
    for (int j = 0; j < 16; ++j) dst[j] = f2b(o[j] * inv);
}

// ---------------------------------------------------------------------------
extern "C" void kernel_launch(void* const* d_in, const int* in_sizes, int n_in,
                              void* d_out, int out_size, void* d_ws, size_t ws_size,
                              hipStream_t stream)
{
    const float* x     = (const float*)d_in[0];
    const float* ctx   = (const float*)d_in[1];
    const float* ln1g  = (const float*)d_in[2];
    const float* ln1b  = (const float*)d_in[3];
    const float* Wattn = (const float*)d_in[4];
    const float* battn = (const float*)d_in[5];
    const float* Wref  = (const float*)d_in[6];
    const float* bref  = (const float*)d_in[7];
    const float* Wproj = (const float*)d_in[8];
    const float* bproj = (const float*)d_in[9];
    const float* ln2g  = (const float*)d_in[10];
    const float* ln2b  = (const float*)d_in[11];
    const float* W1    = (const float*)d_in[12];
    const float* b1    = (const float*)d_in[13];
    const float* W2    = (const float*)d_in[14];
    const float* b2    = (const float*)d_in[15];
    const float* cab   = (const float*)d_in[16];
    const int*   smp   = (const int*)d_in[17];
    float* out = (float*)d_out;

    // ---- workspace layout (float units) ----
    // Time-disjoint overlays:
    //   ff1b (step 7..8, 6291456 fl) overlays qkvb+kvctxb+attnb (all dead
    //   after step 5) at ws+0, ending 6291456 < hb at 7077888 (live step 7).
    //   ctxb (step 0..3) sits in its own 393216-fl slot before wts.
    float* ws = (float*)d_ws;
    unsigned short* qkvb   = (unsigned short*)(ws + 0);          // 4096x2304 bf16 (steps 2-4)
    unsigned short* ff1b   = (unsigned short*)(ws + 0);          // 4096x3072 bf16 (steps 7-8)
    unsigned short* kvctxb = (unsigned short*)(ws + 4718592);    // 1024x1536 bf16
    unsigned short* attnb  = (unsigned short*)(ws + 5505024);    // 4096x768 bf16
    unsigned short* hb     = (unsigned short*)(ws + 7077888);    // 4096x768 bf16
    float*          x1     = ws + 8650752;                       // 4096x768 fp32 (ends 11796480)
    unsigned short* ctxb   = (unsigned short*)(ws + 11796480);   // 1024x768 bf16 (ends 12189696)
    unsigned short* wts    = (unsigned short*)(ws + 12189696);   // bf16 weights, 8257536 ush
    unsigned short* wattnT = wts;                                // 2304x768
    unsigned short* wrefT  = wts + 1769472;                      // 1536x768
    unsigned short* wprojT = wts + 2949120;                      // 768x768
    unsigned short* w1T    = wts + 3538944;                      // 3072x768
    unsigned short* w2T    = wts + 5898240;                      // 768x3072 (ends 8257536 ush = 16318464 fl)

    // 0. weight convert+transpose (fp32 [K][N] -> bf16 [N][K]) + ctx convert
    wconv_t<<<dim3(2304 / 32, 768 / 32), 256, 0, stream>>>(Wattn, wattnT, 768, 2304);
    wconv_t<<<dim3(1536 / 32, 768 / 32), 256, 0, stream>>>(Wref,  wrefT,  768, 1536);
    wconv_t<<<dim3(768 / 32,  768 / 32), 256, 0, stream>>>(Wproj, wprojT, 768, 768);
    wconv_t<<<dim3(3072 / 32, 768 / 32), 256, 0, stream>>>(W1,    w1T,    768, 3072);
    wconv_t<<<dim3(768 / 32, 3072 / 32), 256, 0, stream>>>(W2,    w2T,    3072, 768);
    f2b_vec<<<768, 256, 0, stream>>>(ctx, ctxb, (B_ * C_ * D_) / 4);

    // 1. h = LN1(x)  [bf16]
    ln_kernel<<<B_ * S_, 256, 0, stream>>>(x, ln1g, ln1b, hb);
    // 2. qkv = h @ Wattn + battn  [bf16]
    gemm_mfma<0, 0, 0, 1><<<dim3(18, 32), 256, 0, stream>>>(
        hb, wattnT, battn, nullptr, nullptr, qkvb, 4096, 2304, 768);
    // 3. kvctx = ctx @ Wref + bref  [bf16]
    gemm_mfma<0, 0, 0, 1><<<dim3(12, 8), 256, 0, stream>>>(
        ctxb, wrefT, bref, nullptr, nullptr, kvctxb, 1024, 1536, 768);
    // 4. attention  [bf16 out]
    attn_kernel<<<dim3(S_ / 64, H_, B_), 256, 0, stream>>>(qkvb, kvctxb, cab, smp, attnb);
    // 5. x1 = x + attn @ Wproj + bproj  [fp32]
    gemm_mfma<0, 1, 0, 0><<<dim3(6, 32), 256, 0, stream>>>(
        attnb, wprojT, bproj, x, x1, nullptr, 4096, 768, 768);
    // 6. h = LN2(x1)  [bf16]
    ln_kernel<<<B_ * S_, 256, 0, stream>>>(x1, ln2g, ln2b, hb);
    // 7. ff1 = silu(h @ W1 + b1)  [bf16]
    gemm_mfma<1, 0, 0, 1><<<dim3(24, 32), 256, 0, stream>>>(
        hb, w1T, b1, nullptr, nullptr, ff1b, 4096, 3072, 768);
    // 8. out = slice(x1 + ff1 @ W2 + b2)  [fp32]
    gemm_mfma<0, 1, 1, 0><<<dim3(6, 32), 256, 0, stream>>>(
        ff1b, w2T, b2, x1, out, nullptr, 4096, 768, 3072);
}

// Round 4
// 383.336 us; speedup vs baseline: 5.6059x; 2.4128x over previous
//
#include <hip/hip_runtime.h>
#include <hip/hip_bf16.h>
#include <math.h>

// Problem constants
#define B_   2
#define S_   2048
#define C_   512
#define D_   768
#define H_   12
#define DH_  64
#define DFF_ 3072
#define NS_  (C_ + S_)   // 2560

typedef __attribute__((ext_vector_type(8))) short          bf16x8;
typedef __attribute__((ext_vector_type(4))) float          f32x4;
typedef __attribute__((ext_vector_type(8))) unsigned short us8;
typedef __attribute__((ext_vector_type(4))) unsigned short us4;

static __device__ __forceinline__ unsigned short f2b(float f) {
    unsigned int u = __float_as_uint(f);
    unsigned int r = (u + 0x7FFFu + ((u >> 16) & 1u)) >> 16;   // RNE
    return (unsigned short)r;
}
static __device__ __forceinline__ float b2f(unsigned short u) {
    return __uint_as_float(((unsigned int)u) << 16);
}

// async global->LDS, 16B per lane; lptr must be wave-uniform base
#define ASYNC_LDS16(gp, lp)                                                     \
    __builtin_amdgcn_global_load_lds(                                           \
        (const __attribute__((address_space(1))) void*)(gp),                    \
        (__attribute__((address_space(3))) void*)(lp), 16, 0, 0)

// ---------------------------------------------------------------------------
// LayerNorm over D=768 -> bf16 out. One block (256 threads) per row.
// ---------------------------------------------------------------------------
__global__ __launch_bounds__(256) void ln_kernel(const float* __restrict__ in,
                                                 const float* __restrict__ g,
                                                 const float* __restrict__ bta,
                                                 unsigned short* __restrict__ out)
{
    int row = blockIdx.x;
    int tid = threadIdx.x;
    const float* x = in + (size_t)row * D_;
    float v0 = x[tid], v1 = x[tid + 256], v2 = x[tid + 512];
    float s  = v0 + v1 + v2;
    float s2 = v0 * v0 + v1 * v1 + v2 * v2;
#pragma unroll
    for (int off = 32; off >= 1; off >>= 1) {
        s  += __shfl_down(s,  off, 64);
        s2 += __shfl_down(s2, off, 64);
    }
    __shared__ float sh[8];
    int lane = tid & 63, wv = tid >> 6;
    if (lane == 0) { sh[wv] = s; sh[4 + wv] = s2; }
    __syncthreads();
    s  = sh[0] + sh[1] + sh[2] + sh[3];
    s2 = sh[4] + sh[5] + sh[6] + sh[7];
    float mu   = s * (1.0f / D_);
    float var  = s2 * (1.0f / D_) - mu * mu;
    float rstd = rsqrtf(var + 1e-5f);
    unsigned short* o = out + (size_t)row * D_;
    o[tid]       = f2b((v0 - mu) * rstd * g[tid]       + bta[tid]);
    o[tid + 256] = f2b((v1 - mu) * rstd * g[tid + 256] + bta[tid + 256]);
    o[tid + 512] = f2b((v2 - mu) * rstd * g[tid + 512] + bta[tid + 512]);
}

// ---------------------------------------------------------------------------
// Weight convert+transpose: fp32 [K][N] -> bf16 [N][K]. 32x32 tiles.
// ---------------------------------------------------------------------------
__global__ __launch_bounds__(256) void wconv_t(const float* __restrict__ in,
                                               unsigned short* __restrict__ out,
                                               int K, int N)
{
    __shared__ float t[32][33];
    int n0 = blockIdx.x * 32, k0 = blockIdx.y * 32;
    int tx = threadIdx.x & 31, ty = threadIdx.x >> 5;
#pragma unroll
    for (int i = 0; i < 32; i += 8)
        t[ty + i][tx] = in[(size_t)(k0 + ty + i) * N + n0 + tx];
    __syncthreads();
#pragma unroll
    for (int i = 0; i < 32; i += 8)
        out[(size_t)(n0 + ty + i) * K + k0 + tx] = f2b(t[tx][ty + i]);
}

// fp32 -> bf16 elementwise (n must be multiple of 4)
__global__ __launch_bounds__(256) void f2b_vec(const float* __restrict__ in,
                                               unsigned short* __restrict__ out, int n4)
{
    int i = blockIdx.x * 256 + threadIdx.x;
    if (i < n4) {
        float4 v = ((const float4*)in)[i];
        us4 o = { f2b(v.x), f2b(v.y), f2b(v.z), f2b(v.w) };
        ((us4*)out)[i] = o;
    }
}

// ---------------------------------------------------------------------------
// MFMA bf16 GEMM (m97 structure): C[M,N] = A[M,K] @ BT[N,K]^T + bias
// ---------------------------------------------------------------------------
template <int ACT, int RESID, int SLICE, int OUTBF>
__global__ __launch_bounds__(256) void gemm_mfma(
    const unsigned short* __restrict__ A,    // [M][K] bf16
    const unsigned short* __restrict__ BT,   // [N][K] bf16
    const float* __restrict__ bias,          // [N]
    const float* __restrict__ resid,         // [M][N] fp32 (if RESID)
    float* __restrict__ outf,                // if !OUTBF
    unsigned short* __restrict__ outb,       // if OUTBF
    int M, int N, int K)
{
    __shared__ unsigned short Als[128 * 64];  // 16KB, row-major [row][k]
    __shared__ unsigned short Bls[128 * 64];  // 16KB

    int tid  = threadIdx.x;
    int lane = tid & 63, w = tid >> 6;
    int mb = blockIdx.y * 128, nb = blockIdx.x * 128;
    int wr = w >> 1, wc = w & 1;

    f32x4 acc[4][4];
#pragma unroll
    for (int m = 0; m < 4; ++m)
#pragma unroll
        for (int n = 0; n < 4; ++n)
            acc[m][n] = (f32x4){0.f, 0.f, 0.f, 0.f};

    int srow = w * 32 + (lane >> 3);
    int scol = (lane & 7) * 8;
    const unsigned short* abase = A  + (size_t)(mb + srow) * K + scol;
    const unsigned short* bbase = BT + (size_t)(nb + srow) * K + scol;

    int arow_l = wr * 64 + (lane & 15);
    int brow_l = wc * 64 + (lane & 15);
    int kfrag  = (lane >> 4) * 8;

    for (int kk = 0; kk < K; kk += 64) {
        __syncthreads();
#pragma unroll
        for (int i = 0; i < 4; ++i) {
            ASYNC_LDS16(abase + (size_t)(i * 8) * K + kk,
                        (char*)Als + (w * 32 + i * 8) * 128);
            ASYNC_LDS16(bbase + (size_t)(i * 8) * K + kk,
                        (char*)Bls + (w * 32 + i * 8) * 128);
        }
        __syncthreads();
#pragma unroll
        for (int ks = 0; ks < 64; ks += 32) {
            bf16x8 af[4], bq[4];
#pragma unroll
            for (int m = 0; m < 4; ++m)
                af[m] = *(const bf16x8*)&Als[(arow_l + m * 16) * 64 + ks + kfrag];
#pragma unroll
            for (int n = 0; n < 4; ++n)
                bq[n] = *(const bf16x8*)&Bls[(brow_l + n * 16) * 64 + ks + kfrag];
#pragma unroll
            for (int m = 0; m < 4; ++m)
#pragma unroll
                for (int n = 0; n < 4; ++n)
                    acc[m][n] = __builtin_amdgcn_mfma_f32_16x16x32_bf16(
                        af[m], bq[n], acc[m][n], 0, 0, 0);
        }
    }

#pragma unroll
    for (int m = 0; m < 4; ++m) {
        int grow0 = mb + wr * 64 + m * 16 + ((lane >> 4) << 2);
#pragma unroll
        for (int n = 0; n < 4; ++n) {
            int gcol = nb + wc * 64 + n * 16 + (lane & 15);
            float bv = bias[gcol];
#pragma unroll
            for (int q = 0; q < 4; ++q) {
                float v = acc[m][n][q] + bv;
                if (ACT) v = v / (1.0f + __expf(-v));
                int grow = grow0 + q;
                if (RESID) v += resid[(size_t)grow * N + gcol];
                if (OUTBF) {
                    outb[(size_t)grow * N + gcol] = f2b(v);
                } else if (SLICE) {
                    int bb = grow >> 11, ss = grow & 2047;
                    if (ss > 0)
                        outf[((size_t)(bb * 2047 + ss - 1)) * N + gcol] = v;
                } else {
                    outf[(size_t)grow * N + gcol] = v;
                }
            }
        }
    }
}

// ---------------------------------------------------------------------------
// MFMA fused attention. Block = (q-tile of 64 rows, h, b), 256 thr = 4 waves.
// Wave w owns q-rows [w*16, w*16+16). Per 64-key tile:
//   K: LDS [64][64] bf16, XOR-16B swizzled via pre-swizzled global source
//      (linear global_load_lds dest).
//   QK^T: mfma_f32_16x16x32_bf16, A=Q(regs), B=K(LDS). D-layout: col=key frag
//      (lane&15), row=q (lane>>4)*4+reg -> softmax state m,l lane-local.
//   P: bf16, wave-private LDS rows, same XOR swizzle; re-read as A-frags.
//   V: LDS transposed [d][k] stride 72 (16B-aligned rows), scalar u16 writes.
//   PV: A=P, B=V^T; O accumulates in D-layout with same q mapping as S.
// Two barriers/tile; next-tile staging (K async + V->regs) issued under PV.
// ---------------------------------------------------------------------------
__global__ __launch_bounds__(256) void attn_mfma(const unsigned short* __restrict__ qkv,
                                                 const unsigned short* __restrict__ kvctx,
                                                 const float* __restrict__ cabp,
                                                 const int* __restrict__ smpp,
                                                 unsigned short* __restrict__ aout)
{
    __shared__ unsigned short Kls[64 * 64];   // 8KB swizzled K tile
    __shared__ unsigned short Vt [64 * 72];   // 9KB V^T tile [d][k], stride 72
    __shared__ unsigned short Pls[64 * 64];   // 8KB swizzled P (wave-private rows)

    int qt = 31 - blockIdx.x;                 // LPT: long blocks dispatch first
    int h = blockIdx.y, b = blockIdx.z;
    int tid = threadIdx.x;
    int l = tid & 63, w = tid >> 6;
    int g = l >> 4, lc = l & 15;
    float cab = *cabp;
    int   smp = *smpp;
    int qbase = qt * 64;

    // --- Q fragments in registers: q = qbase + w*16 + lc, dh = ks*32+g*8+i ---
    bf16x8 qf[2];
    {
        const unsigned short* qp = qkv + ((size_t)(b * S_ + qbase + w * 16 + lc)) * (3 * D_)
                                       + h * DH_ + g * 8;
        qf[0] = *(const bf16x8*)(qp);
        qf[1] = *(const bf16x8*)(qp + 32);
    }

    f32x4 acc[4];
#pragma unroll
    for (int n = 0; n < 4; ++n) acc[n] = (f32x4){0.f, 0.f, 0.f, 0.f};
    float mrow[4], lrow[4];
#pragma unroll
    for (int e = 0; e < 4; ++e) { mrow[e] = -1e30f; lrow[e] = 0.f; }

    // staging lane geometry
    int colu = 8 * ((l & 7) ^ (l >> 3));       // pre-swizzled global col (bf16)
    int kvr  = tid >> 3;                       // V: k-row 0..31 (+32 on 2nd half)
    int d0   = (tid & 7) * 8;                  // V: d chunk base
    us8 vreg0, vreg1;

    int ntiles = qt + 9;

#define STAGE_TILE(TT)                                                                   \
    {                                                                                    \
        int kb2 = (TT) * 64;                                                             \
        bool isctx = (kb2 < C_);                                                         \
        _Pragma("unroll")                                                                \
        for (int s2 = 0; s2 < 2; ++s2) {                                                 \
            int s = w * 2 + s2;                                                          \
            int kj = kb2 + s * 8 + (l >> 3);                                             \
            const unsigned short* src = isctx                                            \
                ? kvctx + ((size_t)(b * C_ + kj)) * (2 * D_) + h * DH_ + colu            \
                : qkv + ((size_t)(b * S_ + kj - C_)) * (3 * D_) + D_ + h * DH_ + colu;   \
            ASYNC_LDS16(src, (char*)Kls + s * 1024);                                     \
        }                                                                                \
        int kj0 = kb2 + kvr, kj1 = kb2 + 32 + kvr;                                       \
        vreg0 = *(const us8*)(isctx                                                      \
            ? kvctx + ((size_t)(b * C_ + kj0)) * (2 * D_) + D_ + h * DH_ + d0            \
            : qkv + ((size_t)(b * S_ + kj0 - C_)) * (3 * D_) + 2 * D_ + h * DH_ + d0);   \
        vreg1 = *(const us8*)(isctx                                                      \
            ? kvctx + ((size_t)(b * C_ + kj1)) * (2 * D_) + D_ + h * DH_ + d0            \
            : qkv + ((size_t)(b * S_ + kj1 - C_)) * (3 * D_) + 2 * D_ + h * DH_ + d0);   \
    }

    STAGE_TILE(0)

    for (int t = 0; t < ntiles; ++t) {
        int kb = t * 64;
        __syncthreads();   // BARRIER_C: prev PV done everywhere; staging visible

        // ---- V^T scatter from regs: Vt[d][k], k = kvr (+32), d = d0+jj ----
#pragma unroll
        for (int jj = 0; jj < 8; ++jj) Vt[(d0 + jj) * 72 + kvr]      = vreg0[jj];
#pragma unroll
        for (int jj = 0; jj < 8; ++jj) Vt[(d0 + jj) * 72 + 32 + kvr] = vreg1[jj];

        // ---- QK^T: S[16q x 64k] per wave ----
        f32x4 s4[4];
#pragma unroll
        for (int nf = 0; nf < 4; ++nf) s4[nf] = (f32x4){0.f, 0.f, 0.f, 0.f};
#pragma unroll
        for (int ks = 0; ks < 2; ++ks) {
#pragma unroll
            for (int nf = 0; nf < 4; ++nf) {
                int key = nf * 16 + lc;
                bf16x8 kf = *(const bf16x8*)&Kls[key * 64 +
                               ((ks * 32 + g * 8) ^ ((key & 7) << 3))];
                s4[nf] = __builtin_amdgcn_mfma_f32_16x16x32_bf16(qf[ks], kf, s4[nf], 0, 0, 0);
            }
        }

        // ---- mask + bias + online softmax (q = qbase + w*16 + g*4 + e) ----
        float pv[4][4];   // [nf][e]
        float tmax[4] = {-1e30f, -1e30f, -1e30f, -1e30f};
#pragma unroll
        for (int nf = 0; nf < 4; ++nf) {
            int kj = kb + nf * 16 + lc;
#pragma unroll
            for (int e = 0; e < 4; ++e) {
                int qi = qbase + w * 16 + g * 4 + e;
                bool valid = (kj <= qi + C_) && !((smp > 0) && (kj == qi));
                float v = valid ? s4[nf][e] : -10000.0f;
                if (kj < C_) v += cab;
                pv[nf][e] = v;
                tmax[e] = fmaxf(tmax[e], v);
            }
        }
#pragma unroll
        for (int e = 0; e < 4; ++e) {
            tmax[e] = fmaxf(tmax[e], __shfl_xor(tmax[e], 1));
            tmax[e] = fmaxf(tmax[e], __shfl_xor(tmax[e], 2));
            tmax[e] = fmaxf(tmax[e], __shfl_xor(tmax[e], 4));
            tmax[e] = fmaxf(tmax[e], __shfl_xor(tmax[e], 8));
        }
        float psum[4];
#pragma unroll
        for (int e = 0; e < 4; ++e) {
            float mnew = fmaxf(mrow[e], tmax[e]);
            float scale = __expf(mrow[e] - mnew);
            mrow[e] = mnew;
            psum[e] = 0.f;
#pragma unroll
            for (int nf = 0; nf < 4; ++nf) {
                float p = __expf(pv[nf][e] - mnew);
                pv[nf][e] = p;
                psum[e] += p;
            }
#pragma unroll
            for (int nf2 = 0; nf2 < 4; ++nf2) acc[nf2][e] *= scale;
            lrow[e] = lrow[e] * scale;
        }
#pragma unroll
        for (int e = 0; e < 4; ++e) {
            psum[e] += __shfl_xor(psum[e], 1);
            psum[e] += __shfl_xor(psum[e], 2);
            psum[e] += __shfl_xor(psum[e], 4);
            psum[e] += __shfl_xor(psum[e], 8);
            lrow[e] += psum[e];
        }

        // ---- P -> bf16 -> wave-private swizzled LDS rows ----
#pragma unroll
        for (int e = 0; e < 4; ++e) {
            int qloc = w * 16 + g * 4 + e;
#pragma unroll
            for (int nf = 0; nf < 4; ++nf)
                Pls[qloc * 64 + ((nf * 16 + lc) ^ ((qloc & 7) << 3))] = f2b(pv[nf][e]);
        }

        __syncthreads();   // BARRIER_B: all V^T writes + P visible

        // ---- stage next tile under PV ----
        if (t + 1 < ntiles) STAGE_TILE(t + 1)

        // ---- PV: O[16q x 64d] += P @ V ----
        {
            int qa = w * 16 + lc;
#pragma unroll
            for (int ks2 = 0; ks2 < 2; ++ks2) {
                bf16x8 pf = *(const bf16x8*)&Pls[qa * 64 +
                               ((ks2 * 32 + g * 8) ^ ((qa & 7) << 3))];
#pragma unroll
                for (int nf2 = 0; nf2 < 4; ++nf2) {
                    int d = nf2 * 16 + lc;
                    bf16x8 vf = *(const bf16x8*)&Vt[d * 72 + ks2 * 32 + g * 8];
                    acc[nf2] = __builtin_amdgcn_mfma_f32_16x16x32_bf16(pf, vf, acc[nf2], 0, 0, 0);
                }
            }
        }
    }

    // ---- epilogue: O / l, write bf16 ----
#pragma unroll
    for (int e = 0; e < 4; ++e) {
        int q = qbase + w * 16 + g * 4 + e;
        float inv = 1.0f / lrow[e];
        unsigned short* dst = &aout[((size_t)(b * S_ + q)) * D_ + h * DH_];
#pragma unroll
        for (int nf2 = 0; nf2 < 4; ++nf2)
            dst[nf2 * 16 + lc] = f2b(acc[nf2][e] * inv);
    }
#undef STAGE_TILE
}

// ---------------------------------------------------------------------------
extern "C" void kernel_launch(void* const* d_in, const int* in_sizes, int n_in,
                              void* d_out, int out_size, void* d_ws, size_t ws_size,
                              hipStream_t stream)
{
    const float* x     = (const float*)d_in[0];
    const float* ctx   = (const float*)d_in[1];
    const float* ln1g  = (const float*)d_in[2];
    const float* ln1b  = (const float*)d_in[3];
    const float* Wattn = (const float*)d_in[4];
    const float* battn = (const float*)d_in[5];
    const float* Wref  = (const float*)d_in[6];
    const float* bref  = (const float*)d_in[7];
    const float* Wproj = (const float*)d_in[8];
    const float* bproj = (const float*)d_in[9];
    const float* ln2g  = (const float*)d_in[10];
    const float* ln2b  = (const float*)d_in[11];
    const float* W1    = (const float*)d_in[12];
    const float* b1    = (const float*)d_in[13];
    const float* W2    = (const float*)d_in[14];
    const float* b2    = (const float*)d_in[15];
    const float* cab   = (const float*)d_in[16];
    const int*   smp   = (const int*)d_in[17];
    float* out = (float*)d_out;

    // ---- workspace layout (float units) ----
    float* ws = (float*)d_ws;
    unsigned short* qkvb   = (unsigned short*)(ws + 0);          // 4096x2304 bf16 (steps 2-4)
    unsigned short* ff1b   = (unsigned short*)(ws + 0);          // 4096x3072 bf16 (steps 7-8)
    unsigned short* kvctxb = (unsigned short*)(ws + 4718592);    // 1024x1536 bf16
    unsigned short* attnb  = (unsigned short*)(ws + 5505024);    // 4096x768 bf16
    unsigned short* hb     = (unsigned short*)(ws + 7077888);    // 4096x768 bf16
    float*          x1     = ws + 8650752;                       // 4096x768 fp32 (ends 11796480)
    unsigned short* ctxb   = (unsigned short*)(ws + 11796480);   // 1024x768 bf16 (ends 12189696)
    unsigned short* wts    = (unsigned short*)(ws + 12189696);   // bf16 weights
    unsigned short* wattnT = wts;                                // 2304x768
    unsigned short* wrefT  = wts + 1769472;                      // 1536x768
    unsigned short* wprojT = wts + 2949120;                      // 768x768
    unsigned short* w1T    = wts + 3538944;                      // 3072x768
    unsigned short* w2T    = wts + 5898240;                      // 768x3072

    // 0. weight convert+transpose + ctx convert
    wconv_t<<<dim3(2304 / 32, 768 / 32), 256, 0, stream>>>(Wattn, wattnT, 768, 2304);
    wconv_t<<<dim3(1536 / 32, 768 / 32), 256, 0, stream>>>(Wref,  wrefT,  768, 1536);
    wconv_t<<<dim3(768 / 32,  768 / 32), 256, 0, stream>>>(Wproj, wprojT, 768, 768);
    wconv_t<<<dim3(3072 / 32, 768 / 32), 256, 0, stream>>>(W1,    w1T,    768, 3072);
    wconv_t<<<dim3(768 / 32, 3072 / 32), 256, 0, stream>>>(W2,    w2T,    3072, 768);
    f2b_vec<<<768, 256, 0, stream>>>(ctx, ctxb, (B_ * C_ * D_) / 4);

    // 1. h = LN1(x)
    ln_kernel<<<B_ * S_, 256, 0, stream>>>(x, ln1g, ln1b, hb);
    // 2. qkv = h @ Wattn + battn
    gemm_mfma<0, 0, 0, 1><<<dim3(18, 32), 256, 0, stream>>>(
        hb, wattnT, battn, nullptr, nullptr, qkvb, 4096, 2304, 768);
    // 3. kvctx = ctx @ Wref + bref
    gemm_mfma<0, 0, 0, 1><<<dim3(12, 8), 256, 0, stream>>>(
        ctxb, wrefT, bref, nullptr, nullptr, kvctxb, 1024, 1536, 768);
    // 4. attention (MFMA)
    attn_mfma<<<dim3(S_ / 64, H_, B_), 256, 0, stream>>>(qkvb, kvctxb, cab, smp, attnb);
    // 5. x1 = x + attn @ Wproj + bproj
    gemm_mfma<0, 1, 0, 0><<<dim3(6, 32), 256, 0, stream>>>(
        attnb, wprojT, bproj, x, x1, nullptr, 4096, 768, 768);
    // 6. h = LN2(x1)
    ln_kernel<<<B_ * S_, 256, 0, stream>>>(x1, ln2g, ln2b, hb);
    // 7. ff1 = silu(h @ W1 + b1)
    gemm_mfma<1, 0, 0, 1><<<dim3(24, 32), 256, 0, stream>>>(
        hb, w1T, b1, nullptr, nullptr, ff1b, 4096, 3072, 768);
    // 8. out = slice(x1 + ff1 @ W2 + b2)
    gemm_mfma<0, 1, 1, 0><<<dim3(6, 32), 256, 0, stream>>>(
        ff1b, w2T, b2, x1, out, nullptr, 4096, 768, 3072);
}

// Round 5
// 356.884 us; speedup vs baseline: 6.0214x; 1.0741x over previous
//
#include <hip/hip_runtime.h>
#include <hip/hip_bf16.h>
#include <math.h>

// Problem constants
#define B_   2
#define S_   2048
#define C_   512
#define D_   768
#define H_   12
#define DH_  64
#define DFF_ 3072
#define NS_  (C_ + S_)   // 2560

typedef __attribute__((ext_vector_type(8))) short          bf16x8;
typedef __attribute__((ext_vector_type(4))) float          f32x4;
typedef __attribute__((ext_vector_type(8))) unsigned short us8;
typedef __attribute__((ext_vector_type(4))) unsigned short us4;

static __device__ __forceinline__ unsigned short f2b(float f) {
    unsigned int u = __float_as_uint(f);
    unsigned int r = (u + 0x7FFFu + ((u >> 16) & 1u)) >> 16;   // RNE
    return (unsigned short)r;
}
static __device__ __forceinline__ float b2f(unsigned short u) {
    return __uint_as_float(((unsigned int)u) << 16);
}

// async global->LDS, 16B per lane; lptr must be wave-uniform base
#define ASYNC_LDS16(gp, lp)                                                     \
    __builtin_amdgcn_global_load_lds(                                           \
        (const __attribute__((address_space(1))) void*)(gp),                    \
        (__attribute__((address_space(3))) void*)(lp), 16, 0, 0)

// ---------------------------------------------------------------------------
// LayerNorm over D=768 -> bf16 out. One block (256 threads) per row.
// ---------------------------------------------------------------------------
__global__ __launch_bounds__(256) void ln_kernel(const float* __restrict__ in,
                                                 const float* __restrict__ g,
                                                 const float* __restrict__ bta,
                                                 unsigned short* __restrict__ out)
{
    int row = blockIdx.x;
    int tid = threadIdx.x;
    const float* x = in + (size_t)row * D_;
    float v0 = x[tid], v1 = x[tid + 256], v2 = x[tid + 512];
    float s  = v0 + v1 + v2;
    float s2 = v0 * v0 + v1 * v1 + v2 * v2;
#pragma unroll
    for (int off = 32; off >= 1; off >>= 1) {
        s  += __shfl_down(s,  off, 64);
        s2 += __shfl_down(s2, off, 64);
    }
    __shared__ float sh[8];
    int lane = tid & 63, wv = tid >> 6;
    if (lane == 0) { sh[wv] = s; sh[4 + wv] = s2; }
    __syncthreads();
    s  = sh[0] + sh[1] + sh[2] + sh[3];
    s2 = sh[4] + sh[5] + sh[6] + sh[7];
    float mu   = s * (1.0f / D_);
    float var  = s2 * (1.0f / D_) - mu * mu;
    float rstd = rsqrtf(var + 1e-5f);
    unsigned short* o = out + (size_t)row * D_;
    o[tid]       = f2b((v0 - mu) * rstd * g[tid]       + bta[tid]);
    o[tid + 256] = f2b((v1 - mu) * rstd * g[tid + 256] + bta[tid + 256]);
    o[tid + 512] = f2b((v2 - mu) * rstd * g[tid + 512] + bta[tid + 512]);
}

// ---------------------------------------------------------------------------
// Weight convert+transpose: fp32 [K][N] -> bf16 [N][K]. 32x32 tiles.
// ---------------------------------------------------------------------------
__global__ __launch_bounds__(256) void wconv_t(const float* __restrict__ in,
                                               unsigned short* __restrict__ out,
                                               int K, int N)
{
    __shared__ float t[32][33];
    int n0 = blockIdx.x * 32, k0 = blockIdx.y * 32;
    int tx = threadIdx.x & 31, ty = threadIdx.x >> 5;
#pragma unroll
    for (int i = 0; i < 32; i += 8)
        t[ty + i][tx] = in[(size_t)(k0 + ty + i) * N + n0 + tx];
    __syncthreads();
#pragma unroll
    for (int i = 0; i < 32; i += 8)
        out[(size_t)(n0 + ty + i) * K + k0 + tx] = f2b(t[tx][ty + i]);
}

// fp32 -> bf16 elementwise (n must be multiple of 4)
__global__ __launch_bounds__(256) void f2b_vec(const float* __restrict__ in,
                                               unsigned short* __restrict__ out, int n4)
{
    int i = blockIdx.x * 256 + threadIdx.x;
    if (i < n4) {
        float4 v = ((const float4*)in)[i];
        us4 o = { f2b(v.x), f2b(v.y), f2b(v.z), f2b(v.w) };
        ((us4*)out)[i] = o;
    }
}

// ---------------------------------------------------------------------------
// MFMA bf16 GEMM (m97 structure): C[M,N] = A[M,K] @ BT[N,K]^T + bias
// ---------------------------------------------------------------------------
template <int ACT, int RESID, int SLICE, int OUTBF>
__global__ __launch_bounds__(256) void gemm_mfma(
    const unsigned short* __restrict__ A,    // [M][K] bf16
    const unsigned short* __restrict__ BT,   // [N][K] bf16
    const float* __restrict__ bias,          // [N]
    const float* __restrict__ resid,         // [M][N] fp32 (if RESID)
    float* __restrict__ outf,                // if !OUTBF
    unsigned short* __restrict__ outb,       // if OUTBF
    int M, int N, int K)
{
    __shared__ unsigned short Als[128 * 64];  // 16KB, row-major [row][k]
    __shared__ unsigned short Bls[128 * 64];  // 16KB

    int tid  = threadIdx.x;
    int lane = tid & 63, w = tid >> 6;
    int mb = blockIdx.y * 128, nb = blockIdx.x * 128;
    int wr = w >> 1, wc = w & 1;

    f32x4 acc[4][4];
#pragma unroll
    for (int m = 0; m < 4; ++m)
#pragma unroll
        for (int n = 0; n < 4; ++n)
            acc[m][n] = (f32x4){0.f, 0.f, 0.f, 0.f};

    int srow = w * 32 + (lane >> 3);
    int scol = (lane & 7) * 8;
    const unsigned short* abase = A  + (size_t)(mb + srow) * K + scol;
    const unsigned short* bbase = BT + (size_t)(nb + srow) * K + scol;

    int arow_l = wr * 64 + (lane & 15);
    int brow_l = wc * 64 + (lane & 15);
    int kfrag  = (lane >> 4) * 8;

    for (int kk = 0; kk < K; kk += 64) {
        __syncthreads();
#pragma unroll
        for (int i = 0; i < 4; ++i) {
            ASYNC_LDS16(abase + (size_t)(i * 8) * K + kk,
                        (char*)Als + (w * 32 + i * 8) * 128);
            ASYNC_LDS16(bbase + (size_t)(i * 8) * K + kk,
                        (char*)Bls + (w * 32 + i * 8) * 128);
        }
        __syncthreads();
#pragma unroll
        for (int ks = 0; ks < 64; ks += 32) {
            bf16x8 af[4], bq[4];
#pragma unroll
            for (int m = 0; m < 4; ++m)
                af[m] = *(const bf16x8*)&Als[(arow_l + m * 16) * 64 + ks + kfrag];
#pragma unroll
            for (int n = 0; n < 4; ++n)
                bq[n] = *(const bf16x8*)&Bls[(brow_l + n * 16) * 64 + ks + kfrag];
#pragma unroll
            for (int m = 0; m < 4; ++m)
#pragma unroll
                for (int n = 0; n < 4; ++n)
                    acc[m][n] = __builtin_amdgcn_mfma_f32_16x16x32_bf16(
                        af[m], bq[n], acc[m][n], 0, 0, 0);
        }
    }

#pragma unroll
    for (int m = 0; m < 4; ++m) {
        int grow0 = mb + wr * 64 + m * 16 + ((lane >> 4) << 2);
#pragma unroll
        for (int n = 0; n < 4; ++n) {
            int gcol = nb + wc * 64 + n * 16 + (lane & 15);
            float bv = bias[gcol];
#pragma unroll
            for (int q = 0; q < 4; ++q) {
                float v = acc[m][n][q] + bv;
                if (ACT) v = v / (1.0f + __expf(-v));
                int grow = grow0 + q;
                if (RESID) v += resid[(size_t)grow * N + gcol];
                if (OUTBF) {
                    outb[(size_t)grow * N + gcol] = f2b(v);
                } else if (SLICE) {
                    int bb = grow >> 11, ss = grow & 2047;
                    if (ss > 0)
                        outf[((size_t)(bb * 2047 + ss - 1)) * N + gcol] = v;
                } else {
                    outf[(size_t)grow * N + gcol] = v;
                }
            }
        }
    }
}

// ---------------------------------------------------------------------------
// MFMA fused attention, KVBLK=128. Block = (64 q-rows, h, b), 4 waves.
// Wave w owns q-rows [w*16, w*16+16). Per 128-key tile (2 barriers):
//   K: Kls[128][64] bf16, XOR-16B-chunk swizzle via pre-swizzled global src.
//   QK^T: 16 mfma_16x16x32_bf16; D rows=q (lane>>4)*4+reg -> m,l lane-local.
//   V^T: Vt[d][k'] u16, stride 136, k' = k ^ ((d>>3)<<3)  (write ~2-way).
//   P:  Pls[q][k'] bf16, stride 136, k' = k ^ ((q&7)<<3).
//   PV: 16 mfma, A=P frags, B=Vt frags.
// Next-tile staging (K async + V->regs) issued under PV. s_setprio on MFMA.
// ---------------------------------------------------------------------------
__global__ __launch_bounds__(256) void attn_mfma(const unsigned short* __restrict__ qkv,
                                                 const unsigned short* __restrict__ kvctx,
                                                 const float* __restrict__ cabp,
                                                 const int* __restrict__ smpp,
                                                 unsigned short* __restrict__ aout)
{
    __shared__ unsigned short Kls[128 * 64];   // 16KB swizzled K tile
    __shared__ unsigned short Vt [64 * 136];   // 17KB V^T [d][k'], stride 136
    __shared__ unsigned short Pls[64 * 136];   // 17KB P [q][k'], stride 136

    int qt = 31 - blockIdx.x;                  // LPT: long blocks dispatch first
    int h = blockIdx.y, b = blockIdx.z;
    int tid = threadIdx.x;
    int l = tid & 63, w = tid >> 6;
    int g = l >> 4, lc = l & 15;
    float cab = *cabp;
    int   smp = *smpp;
    int qbase = qt * 64;

    // --- Q fragments: q = qbase + w*16 + lc, dh = ks*32 + g*8 + i ---
    bf16x8 qf0, qf1;
    {
        const unsigned short* qp = qkv + ((size_t)(b * S_ + qbase + w * 16 + lc)) * (3 * D_)
                                       + h * DH_ + g * 8;
        qf0 = *(const bf16x8*)(qp);
        qf1 = *(const bf16x8*)(qp + 32);
    }

    f32x4 acc[4];
#pragma unroll
    for (int n = 0; n < 4; ++n) acc[n] = (f32x4){0.f, 0.f, 0.f, 0.f};
    float mrow[4], lrow[4];
#pragma unroll
    for (int e = 0; e < 4; ++e) { mrow[e] = -1e30f; lrow[e] = 0.f; }

    // staging lane geometry
    int colu = 8 * ((l & 7) ^ (l >> 3));       // pre-swizzled global col (bf16)
    int kvr  = tid >> 3;                       // V: k-row 0..31 (+32/64/96)
    int d0   = (tid & 7) * 8;                  // V: d chunk base
    int dsw  = (tid & 7) << 3;                 // Vt k-swizzle mask for this thread
    us8 vr0, vr1, vr2, vr3;

    int ntiles = (qbase + 576 + 127) >> 7;     // 128-key tiles

#define STAGE_TILE(TT)                                                                   \
    {                                                                                    \
        int kb2 = (TT) * 128;                                                            \
        bool isctx = (kb2 < C_);                                                         \
        _Pragma("unroll")                                                                \
        for (int s2 = 0; s2 < 4; ++s2) {                                                 \
            int s = w * 4 + s2;                                                          \
            int kj = kb2 + s * 8 + (l >> 3);                                             \
            const unsigned short* src = isctx                                            \
                ? kvctx + ((size_t)(b * C_ + kj)) * (2 * D_) + h * DH_ + colu            \
                : qkv + ((size_t)(b * S_ + kj - C_)) * (3 * D_) + D_ + h * DH_ + colu;   \
            ASYNC_LDS16(src, (char*)Kls + s * 1024);                                     \
        }                                                                                \
        int kv0 = kb2 + kvr;                                                             \
        vr0 = *(const us8*)(isctx                                                        \
            ? kvctx + ((size_t)(b * C_ + kv0)) * (2 * D_) + D_ + h * DH_ + d0            \
            : qkv + ((size_t)(b * S_ + kv0 - C_)) * (3 * D_) + 2 * D_ + h * DH_ + d0);   \
        vr1 = *(const us8*)(isctx                                                        \
            ? kvctx + ((size_t)(b * C_ + kv0 + 32)) * (2 * D_) + D_ + h * DH_ + d0       \
            : qkv + ((size_t)(b * S_ + kv0 + 32 - C_)) * (3 * D_) + 2 * D_ + h * DH_ + d0); \
        vr2 = *(const us8*)(isctx                                                        \
            ? kvctx + ((size_t)(b * C_ + kv0 + 64)) * (2 * D_) + D_ + h * DH_ + d0       \
            : qkv + ((size_t)(b * S_ + kv0 + 64 - C_)) * (3 * D_) + 2 * D_ + h * DH_ + d0); \
        vr3 = *(const us8*)(isctx                                                        \
            ? kvctx + ((size_t)(b * C_ + kv0 + 96)) * (2 * D_) + D_ + h * DH_ + d0       \
            : qkv + ((size_t)(b * S_ + kv0 + 96 - C_)) * (3 * D_) + 2 * D_ + h * DH_ + d0); \
    }

    STAGE_TILE(0)

    for (int t = 0; t < ntiles; ++t) {
        int kb = t * 128;
        __syncthreads();   // staging visible; prev PV done reading Vt/Pls

        // ---- V^T scatter: Vt[d][k ^ dsw] (d = d0+jj, k = q*32 + kvr) ----
#pragma unroll
        for (int jj = 0; jj < 8; ++jj) {
            int row = (d0 + jj) * 136;
            Vt[row + ((  0 + kvr) ^ dsw)] = vr0[jj];
            Vt[row + (( 32 + kvr) ^ dsw)] = vr1[jj];
            Vt[row + (( 64 + kvr) ^ dsw)] = vr2[jj];
            Vt[row + (( 96 + kvr) ^ dsw)] = vr3[jj];
        }

        // ---- QK^T: S[16q x 128k] per wave ----
        f32x4 s4[8];
#pragma unroll
        for (int nf = 0; nf < 8; ++nf) s4[nf] = (f32x4){0.f, 0.f, 0.f, 0.f};
        __builtin_amdgcn_s_setprio(1);
#pragma unroll
        for (int nf = 0; nf < 8; ++nf) {
            int key = nf * 16 + lc;
            int ksw = (key & 7) << 3;
            bf16x8 kf0 = *(const bf16x8*)&Kls[key * 64 + ((g * 8) ^ ksw)];
            bf16x8 kf1 = *(const bf16x8*)&Kls[key * 64 + ((32 + g * 8) ^ ksw)];
            s4[nf] = __builtin_amdgcn_mfma_f32_16x16x32_bf16(qf0, kf0, s4[nf], 0, 0, 0);
            s4[nf] = __builtin_amdgcn_mfma_f32_16x16x32_bf16(qf1, kf1, s4[nf], 0, 0, 0);
        }
        __builtin_amdgcn_s_setprio(0);

        // ---- mask + bias + online softmax (q = qbase + w*16 + g*4 + e) ----
        float tmax[4] = {-1e30f, -1e30f, -1e30f, -1e30f};
#pragma unroll
        for (int nf = 0; nf < 8; ++nf) {
            int kj = kb + nf * 16 + lc;
#pragma unroll
            for (int e = 0; e < 4; ++e) {
                int qi = qbase + w * 16 + g * 4 + e;
                bool valid = (kj <= qi + C_) && !((smp > 0) && (kj == qi));
                float v = valid ? s4[nf][e] : -10000.0f;
                if (kj < C_) v += cab;
                s4[nf][e] = v;
                tmax[e] = fmaxf(tmax[e], v);
            }
        }
#pragma unroll
        for (int e = 0; e < 4; ++e) {
            tmax[e] = fmaxf(tmax[e], __shfl_xor(tmax[e], 1));
            tmax[e] = fmaxf(tmax[e], __shfl_xor(tmax[e], 2));
            tmax[e] = fmaxf(tmax[e], __shfl_xor(tmax[e], 4));
            tmax[e] = fmaxf(tmax[e], __shfl_xor(tmax[e], 8));
        }
        float psum[4];
#pragma unroll
        for (int e = 0; e < 4; ++e) {
            float mnew = fmaxf(mrow[e], tmax[e]);
            float scale = __expf(mrow[e] - mnew);
            mrow[e] = mnew;
            psum[e] = 0.f;
#pragma unroll
            for (int nf = 0; nf < 8; ++nf) {
                float p = __expf(s4[nf][e] - mnew);
                s4[nf][e] = p;
                psum[e] += p;
            }
#pragma unroll
            for (int nf2 = 0; nf2 < 4; ++nf2) acc[nf2][e] *= scale;
            lrow[e] *= scale;
        }
#pragma unroll
        for (int e = 0; e < 4; ++e) {
            psum[e] += __shfl_xor(psum[e], 1);
            psum[e] += __shfl_xor(psum[e], 2);
            psum[e] += __shfl_xor(psum[e], 4);
            psum[e] += __shfl_xor(psum[e], 8);
            lrow[e] += psum[e];
        }

        // ---- P -> bf16 -> wave-private LDS rows (stride 136, XOR swz) ----
#pragma unroll
        for (int e = 0; e < 4; ++e) {
            int q = w * 16 + g * 4 + e;
            int qrow = q * 136, qsw = (q & 7) << 3;
#pragma unroll
            for (int nf = 0; nf < 8; ++nf)
                Pls[qrow + ((nf * 16 + lc) ^ qsw)] = f2b(s4[nf][e]);
        }

        __syncthreads();   // Vt/Pls complete; Kls reads done -> safe to restage

        // ---- stage next tile under PV ----
        if (t + 1 < ntiles) STAGE_TILE(t + 1)

        // ---- PV: O[16q x 64d] += P @ V ----
        {
            int qa = w * 16 + lc;
            int qrow = qa * 136, qsw = (qa & 7) << 3;
            __builtin_amdgcn_s_setprio(1);
#pragma unroll
            for (int ks2 = 0; ks2 < 4; ++ks2) {
                bf16x8 pf = *(const bf16x8*)&Pls[qrow + ((ks2 * 32 + g * 8) ^ qsw)];
#pragma unroll
                for (int nf2 = 0; nf2 < 4; ++nf2) {
                    int d = nf2 * 16 + lc;
                    bf16x8 vf = *(const bf16x8*)&Vt[d * 136 +
                                   ((ks2 * 32 + g * 8) ^ (((d >> 3) & 7) << 3))];
                    acc[nf2] = __builtin_amdgcn_mfma_f32_16x16x32_bf16(pf, vf, acc[nf2], 0, 0, 0);
                }
            }
            __builtin_amdgcn_s_setprio(0);
        }
    }

    // ---- epilogue: O / l, write bf16 ----
#pragma unroll
    for (int e = 0; e < 4; ++e) {
        int q = qbase + w * 16 + g * 4 + e;
        float inv = 1.0f / lrow[e];
        unsigned short* dst = &aout[((size_t)(b * S_ + q)) * D_ + h * DH_];
#pragma unroll
        for (int nf2 = 0; nf2 < 4; ++nf2)
            dst[nf2 * 16 + lc] = f2b(acc[nf2][e] * inv);
    }
#undef STAGE_TILE
}

// ---------------------------------------------------------------------------
extern "C" void kernel_launch(void* const* d_in, const int* in_sizes, int n_in,
                              void* d_out, int out_size, void* d_ws, size_t ws_size,
                              hipStream_t stream)
{
    const float* x     = (const float*)d_in[0];
    const float* ctx   = (const float*)d_in[1];
    const float* ln1g  = (const float*)d_in[2];
    const float* ln1b  = (const float*)d_in[3];
    const float* Wattn = (const float*)d_in[4];
    const float* battn = (const float*)d_in[5];
    const float* Wref  = (const float*)d_in[6];
    const float* bref  = (const float*)d_in[7];
    const float* Wproj = (const float*)d_in[8];
    const float* bproj = (const float*)d_in[9];
    const float* ln2g  = (const float*)d_in[10];
    const float* ln2b  = (const float*)d_in[11];
    const float* W1    = (const float*)d_in[12];
    const float* b1    = (const float*)d_in[13];
    const float* W2    = (const float*)d_in[14];
    const float* b2    = (const float*)d_in[15];
    const float* cab   = (const float*)d_in[16];
    const int*   smp   = (const int*)d_in[17];
    float* out = (float*)d_out;

    // ---- workspace layout (float units) ----
    float* ws = (float*)d_ws;
    unsigned short* qkvb   = (unsigned short*)(ws + 0);          // 4096x2304 bf16 (steps 2-4)
    unsigned short* ff1b   = (unsigned short*)(ws + 0);          // 4096x3072 bf16 (steps 7-8)
    unsigned short* kvctxb = (unsigned short*)(ws + 4718592);    // 1024x1536 bf16
    unsigned short* attnb  = (unsigned short*)(ws + 5505024);    // 4096x768 bf16
    unsigned short* hb     = (unsigned short*)(ws + 7077888);    // 4096x768 bf16
    float*          x1     = ws + 8650752;                       // 4096x768 fp32 (ends 11796480)
    unsigned short* ctxb   = (unsigned short*)(ws + 11796480);   // 1024x768 bf16 (ends 12189696)
    unsigned short* wts    = (unsigned short*)(ws + 12189696);   // bf16 weights
    unsigned short* wattnT = wts;                                // 2304x768
    unsigned short* wrefT  = wts + 1769472;                      // 1536x768
    unsigned short* wprojT = wts + 2949120;                      // 768x768
    unsigned short* w1T    = wts + 3538944;                      // 3072x768
    unsigned short* w2T    = wts + 5898240;                      // 768x3072

    // 0. weight convert+transpose + ctx convert
    wconv_t<<<dim3(2304 / 32, 768 / 32), 256, 0, stream>>>(Wattn, wattnT, 768, 2304);
    wconv_t<<<dim3(1536 / 32, 768 / 32), 256, 0, stream>>>(Wref,  wrefT,  768, 1536);
    wconv_t<<<dim3(768 / 32,  768 / 32), 256, 0, stream>>>(Wproj, wprojT, 768, 768);
    wconv_t<<<dim3(3072 / 32, 768 / 32), 256, 0, stream>>>(W1,    w1T,    768, 3072);
    wconv_t<<<dim3(768 / 32, 3072 / 32), 256, 0, stream>>>(W2,    w2T,    3072, 768);
    f2b_vec<<<768, 256, 0, stream>>>(ctx, ctxb, (B_ * C_ * D_) / 4);

    // 1. h = LN1(x)
    ln_kernel<<<B_ * S_, 256, 0, stream>>>(x, ln1g, ln1b, hb);
    // 2. qkv = h @ Wattn + battn
    gemm_mfma<0, 0, 0, 1><<<dim3(18, 32), 256, 0, stream>>>(
        hb, wattnT, battn, nullptr, nullptr, qkvb, 4096, 2304, 768);
    // 3. kvctx = ctx @ Wref + bref
    gemm_mfma<0, 0, 0, 1><<<dim3(12, 8), 256, 0, stream>>>(
        ctxb, wrefT, bref, nullptr, nullptr, kvctxb, 1024, 1536, 768);
    // 4. attention (MFMA, KVBLK=128)
    attn_mfma<<<dim3(S_ / 64, H_, B_), 256, 0, stream>>>(qkvb, kvctxb, cab, smp, attnb);
    // 5. x1 = x + attn @ Wproj + bproj
    gemm_mfma<0, 1, 0, 0><<<dim3(6, 32), 256, 0, stream>>>(
        attnb, wprojT, bproj, x, x1, nullptr, 4096, 768, 768);
    // 6. h = LN2(x1)
    ln_kernel<<<B_ * S_, 256, 0, stream>>>(x1, ln2g, ln2b, hb);
    // 7. ff1 = silu(h @ W1 + b1)
    gemm_mfma<1, 0, 0, 1><<<dim3(24, 32), 256, 0, stream>>>(
        hb, w1T, b1, nullptr, nullptr, ff1b, 4096, 3072, 768);
    // 8. out = slice(x1 + ff1 @ W2 + b2)
    gemm_mfma<0, 1, 1, 0><<<dim3(6, 32), 256, 0, stream>>>(
        ff1b, w2T, b2, x1, out, nullptr, 4096, 768, 3072);
}